// Round 6
// baseline (172.471 us; speedup 1.0000x reference)
//
#include <hip/hip_runtime.h>

#define N_NODES 4096
#define EDGES   16384
#define PHI     64
#define EPS_F   1e-8f
#define BETA_F  0.5f
#define NCHUNK  16
#define WCHUNK  256   // 256 bf16 cols = 512 B per row-chunk; slab = 2 MB (half an XCD L2)

__device__ __forceinline__ float wave_sum(float v) {
#pragma unroll
    for (int off = 32; off > 0; off >>= 1) v += __shfl_xor(v, off, 64);
    return v;
}

__device__ __forceinline__ unsigned int pack_bf16(float f) {
    unsigned int u = __float_as_uint(f);
    u += 0x7fffu + ((u >> 16) & 1u);   // round-to-nearest-even
    return u >> 16;
}

// k0 (fallback paths only): f_mean, f_mean^2
__global__ void k_prep(const float* __restrict__ f0, const float* __restrict__ f1,
                       float* __restrict__ fm, float* __restrict__ wsq) {
    int i = blockIdx.x * blockDim.x + threadIdx.x;
    if (i < N_NODES) {
        float m = 0.5f * (f0[i] + f1[i]);
        fm[i]  = m;
        wsq[i] = m * m;
    }
}

// k1: per row v: B[v,:] = bf16(A[v,:]*fm), dnorm[v] = ||A[v,:]*fm + eps||
__global__ void __launch_bounds__(256) k_rows_fast(const float* __restrict__ A,
                                                   const float* __restrict__ f0,
                                                   const float* __restrict__ f1,
                                                   unsigned short* __restrict__ B,
                                                   float* __restrict__ dnorm) {
    int row = blockIdx.x;
    const float4* a4  = (const float4*)(A + (size_t)row * N_NODES);
    const float4* f04 = (const float4*)f0;
    const float4* f14 = (const float4*)f1;
    uint2* b2 = (uint2*)(B + (size_t)row * N_NODES);
    int t = threadIdx.x;
    float acc = 0.f;
#pragma unroll
    for (int i = 0; i < 4; ++i) {
        int idx = i * 256 + t;
        float4 a = a4[idx];
        float4 fa = f04[idx];
        float4 fb = f14[idx];
        float fx = 0.5f * (fa.x + fb.x), fy = 0.5f * (fa.y + fb.y);
        float fz = 0.5f * (fa.z + fb.z), fw = 0.5f * (fa.w + fb.w);
        float b0 = a.x * fx, b1 = a.y * fy, b2v = a.z * fz, b3 = a.w * fw;
        float e0 = b0 + EPS_F, e1 = b1 + EPS_F, e2 = b2v + EPS_F, e3 = b3 + EPS_F;
        acc += e0 * e0 + e1 * e1 + e2 * e2 + e3 * e3;
        uint2 p;
        p.x = (pack_bf16(b1) << 16) | pack_bf16(b0);
        p.y = (pack_bf16(b3) << 16) | pack_bf16(b2v);
        b2[idx] = p;
    }
    acc = wave_sum(acc);
    __shared__ float red[4];
    if ((t & 63) == 0) red[t >> 6] = acc;
    __syncthreads();
    if (t == 0) dnorm[row] = sqrtf(red[0] + red[1] + red[2] + red[3]);
}

// k1 slow: dnorm only
__global__ void __launch_bounds__(256) k_rows_slow(const float* __restrict__ A,
                                                   const float* __restrict__ fm,
                                                   float* __restrict__ dnorm) {
    int row = blockIdx.x;
    const float4* a4  = (const float4*)(A + (size_t)row * N_NODES);
    const float4* fm4 = (const float4*)fm;
    int t = threadIdx.x;
    float acc = 0.f;
#pragma unroll
    for (int i = 0; i < 4; ++i) {
        int idx = i * 256 + t;
        float4 a = a4[idx];
        float4 f = fm4[idx];
        float e0 = a.x * f.x + EPS_F, e1 = a.y * f.y + EPS_F;
        float e2 = a.z * f.z + EPS_F, e3 = a.w * f.w + EPS_F;
        acc += e0 * e0 + e1 * e1 + e2 * e2 + e3 * e3;
    }
    acc = wave_sum(acc);
    __shared__ float red[4];
    if ((t & 63) == 0) red[t >> 6] = acc;
    __syncthreads();
    if (t == 0) dnorm[row] = sqrtf(red[0] + red[1] + red[2] + red[3]);
}

// Shared epilogue: given x = out_n, run both MLPs wave-parallel (lane = hidden idx)
__device__ __forceinline__ void mlp_epilogue(float x, int lid, int e, int lane,
                                             const float* __restrict__ p1w1, const float* __restrict__ p1b1,
                                             const float* __restrict__ p1w2, const float* __restrict__ p1b2,
                                             const float* __restrict__ p2w1, const float* __restrict__ p2b1,
                                             const float* __restrict__ p2w2, const float* __restrict__ p2b2,
                                             float* __restrict__ out) {
    int wi = lid * PHI + lane;
    float h1 = fmaxf(fmaf(x, p1w1[wi], p1b1[wi]), 0.f);
    float y1 = wave_sum(h1 * p1w2[wi]) + p1b2[lid];
    float sl1 = BETA_F * y1;   // LM = 1.0
    float h2 = fmaxf(fmaf(sl1, p2w1[wi], p2b1[wi]), 0.f);
    float y2 = wave_sum(h2 * p2w2[wi]) + p2b2[lid];
    if (lane == 0) out[lid * EDGES + e] = y2;
}

// k2: PHASE-MAJOR chunking. chunk = blk >> 10: at any instant the resident
// blocks work on 1-2 chunks; each 2 MB slab gets replicated into every XCD's
// L2 (two consecutive slabs fit in 4 MB), so steady-state reads are local-L2
// hits instead of L3 thrash. 8 lanes per edge, 8 edges per wave, all 8 loads
// staged up front; __launch_bounds__(256,8) -> <=64 VGPR, 8 waves/SIMD.
__global__ void __launch_bounds__(256, 8) k_edges_chunk(
        const unsigned short* __restrict__ B,
        const int* __restrict__ src0, const int* __restrict__ dst0,
        const int* __restrict__ src1, const int* __restrict__ dst1,
        float* __restrict__ P) {
    int blk   = blockIdx.x;
    int chunk = blk >> 10;                     // [0, 16): phase-major
    int slot  = blk & 1023;                    // [0, 1024)
    int wave  = threadIdx.x >> 6;
    int lane  = threadIdx.x & 63;
    int g     = lane >> 3;                     // edge group within wave [0,8)
    int sub   = lane & 7;                      // lane within group

    int ge  = slot * 32 + wave * 8 + g;        // [0, 32768); 8-aligned per wave
    int lid = ge >> 14;
    int e   = ge & (EDGES - 1);
    int s = lid ? src1[e] : src0[e];
    int d = lid ? dst1[e] : dst0[e];

    const uint4* rs = (const uint4*)(B + (size_t)s * N_NODES + chunk * WCHUNK) + sub;
    const uint4* rd = (const uint4*)(B + (size_t)d * N_NODES + chunk * WCHUNK) + sub;

    uint4 us[4], ud[4];
#pragma unroll
    for (int i = 0; i < 4; ++i) {
        us[i] = rs[i * 8];
        ud[i] = rd[i * 8];
    }
    float acc = 0.f;
#pragma unroll
    for (int i = 0; i < 4; ++i) {
#define ACC_U(U, V)                                                    \
        {                                                              \
            float sl = __uint_as_float((U) << 16);                     \
            float sh = __uint_as_float((U) & 0xffff0000u);             \
            float dl = __uint_as_float((V) << 16);                     \
            float dh = __uint_as_float((V) & 0xffff0000u);             \
            acc = fmaf(sl, dl, acc);                                   \
            acc = fmaf(sh, dh, acc);                                   \
        }
        ACC_U(us[i].x, ud[i].x); ACC_U(us[i].y, ud[i].y);
        ACC_U(us[i].z, ud[i].z); ACC_U(us[i].w, ud[i].w);
#undef ACC_U
    }
    // 8-lane group reduce (3 steps, shared across all 8 edges of the wave)
    acc += __shfl_xor(acc, 1, 64);
    acc += __shfl_xor(acc, 2, 64);
    acc += __shfl_xor(acc, 4, 64);
    if (sub == 0) P[(size_t)chunk * (2 * EDGES) + ge] = acc;   // contiguous per wave
}

// k3: reduce 16 partials per edge, normalize, run both MLPs
__global__ void __launch_bounds__(256) k_finish(
        const float* __restrict__ P, const float* __restrict__ dnorm,
        const int* __restrict__ src0, const int* __restrict__ dst0,
        const int* __restrict__ src1, const int* __restrict__ dst1,
        const float* __restrict__ p1w1, const float* __restrict__ p1b1,
        const float* __restrict__ p1w2, const float* __restrict__ p1b2,
        const float* __restrict__ p2w1, const float* __restrict__ p2b1,
        const float* __restrict__ p2w2, const float* __restrict__ p2b2,
        float* __restrict__ out) {
    int gw   = (int)((blockIdx.x * blockDim.x + threadIdx.x) >> 6);   // [0, 32768)
    int lane = threadIdx.x & 63;
    int lid  = gw >> 14;
    int e    = gw & (EDGES - 1);
    int s = lid ? src1[e] : src0[e];
    int d = lid ? dst1[e] : dst0[e];
    float acc = 0.f;
#pragma unroll
    for (int c = 0; c < NCHUNK; ++c) acc += P[(size_t)c * (2 * EDGES) + gw];
    float x = acc / (dnorm[s] * dnorm[d]);
    mlp_epilogue(x, lid, e, lane, p1w1, p1b1, p1w2, p1b2, p2w1, p2b1, p2w2, p2b2, out);
}

// Round-2 fallback: one wave per edge over full rows (monolithic)
__global__ void __launch_bounds__(256) k_edges_fast(
        const unsigned short* __restrict__ B, const float* __restrict__ dnorm,
        const int* __restrict__ src0, const int* __restrict__ dst0,
        const int* __restrict__ src1, const int* __restrict__ dst1,
        const float* __restrict__ p1w1, const float* __restrict__ p1b1,
        const float* __restrict__ p1w2, const float* __restrict__ p1b2,
        const float* __restrict__ p2w1, const float* __restrict__ p2b1,
        const float* __restrict__ p2w2, const float* __restrict__ p2b2,
        float* __restrict__ out) {
    int gw   = (int)((blockIdx.x * blockDim.x + threadIdx.x) >> 6);
    int lane = threadIdx.x & 63;
    int lid  = gw >> 14;
    int e    = gw & (EDGES - 1);
    int s = lid ? src1[e] : src0[e];
    int d = lid ? dst1[e] : dst0[e];
    const uint4* rs = (const uint4*)(B + (size_t)s * N_NODES);
    const uint4* rd = (const uint4*)(B + (size_t)d * N_NODES);
    float acc = 0.f;
#pragma unroll
    for (int i = 0; i < 8; ++i) {
        uint4 us = rs[i * 64 + lane];
        uint4 ud = rd[i * 64 + lane];
#define ACC_U(U, V)                                                    \
        {                                                              \
            float sl = __uint_as_float((U) << 16);                     \
            float sh = __uint_as_float((U) & 0xffff0000u);             \
            float dl = __uint_as_float((V) << 16);                     \
            float dh = __uint_as_float((V) & 0xffff0000u);             \
            acc = fmaf(sl, dl, acc);                                   \
            acc = fmaf(sh, dh, acc);                                   \
        }
        ACC_U(us.x, ud.x); ACC_U(us.y, ud.y); ACC_U(us.z, ud.z); ACC_U(us.w, ud.w);
#undef ACC_U
    }
    acc = wave_sum(acc);
    float x = acc / (dnorm[s] * dnorm[d]);
    mlp_epilogue(x, lid, e, lane, p1w1, p1b1, p1w2, p1b2, p2w1, p2b1, p2w2, p2b2, out);
}

// Slow fallback: fp32 rows of A, weight w = fm^2 staged in LDS
__global__ void __launch_bounds__(256) k_edges_slow(
        const float* __restrict__ A, const float* __restrict__ wsq,
        const float* __restrict__ dnorm,
        const int* __restrict__ src0, const int* __restrict__ dst0,
        const int* __restrict__ src1, const int* __restrict__ dst1,
        const float* __restrict__ p1w1, const float* __restrict__ p1b1,
        const float* __restrict__ p1w2, const float* __restrict__ p1b2,
        const float* __restrict__ p2w1, const float* __restrict__ p2b1,
        const float* __restrict__ p2w2, const float* __restrict__ p2b2,
        float* __restrict__ out) {
    __shared__ float wl[N_NODES];
    int t = threadIdx.x;
    const float4* w4 = (const float4*)wsq;
    float4* wl4 = (float4*)wl;
    for (int i = t; i < N_NODES / 4; i += 256) wl4[i] = w4[i];
    __syncthreads();

    int gw   = (int)((blockIdx.x * blockDim.x + t) >> 6);
    int lane = t & 63;
    int lid  = gw >> 14;
    int e    = gw & (EDGES - 1);
    int s = lid ? src1[e] : src0[e];
    int d = lid ? dst1[e] : dst0[e];
    const float4* rs = (const float4*)(A + (size_t)s * N_NODES);
    const float4* rd = (const float4*)(A + (size_t)d * N_NODES);
    float acc = 0.f;
#pragma unroll
    for (int i = 0; i < 16; ++i) {
        int idx = i * 64 + lane;
        float4 a = rs[idx];
        float4 b = rd[idx];
        float4 w = wl4[idx];
        acc = fmaf(a.x * b.x, w.x, acc);
        acc = fmaf(a.y * b.y, w.y, acc);
        acc = fmaf(a.z * b.z, w.z, acc);
        acc = fmaf(a.w * b.w, w.w, acc);
    }
    acc = wave_sum(acc);
    float x = acc / (dnorm[s] * dnorm[d]);
    mlp_epilogue(x, lid, e, lane, p1w1, p1b1, p1w2, p1b2, p2w1, p2b1, p2w2, p2b2, out);
}

extern "C" void kernel_launch(void* const* d_in, const int* in_sizes, int n_in,
                              void* d_out, int out_size, void* d_ws, size_t ws_size,
                              hipStream_t stream) {
    const float* A    = (const float*)d_in[0];
    const int*   src0 = (const int*)d_in[1];
    const int*   dst0 = (const int*)d_in[2];
    const int*   src1 = (const int*)d_in[3];
    const int*   dst1 = (const int*)d_in[4];
    const float* f0   = (const float*)d_in[5];
    const float* f1   = (const float*)d_in[6];
    const float* p1w1 = (const float*)d_in[7];
    const float* p1b1 = (const float*)d_in[8];
    const float* p1w2 = (const float*)d_in[9];
    const float* p1b2 = (const float*)d_in[10];
    const float* p2w1 = (const float*)d_in[11];
    const float* p2b1 = (const float*)d_in[12];
    const float* p2w2 = (const float*)d_in[13];
    const float* p2b2 = (const float*)d_in[14];
    float* out = (float*)d_out;

    float* ws  = (float*)d_ws;
    float* fm  = ws;
    float* wsq = ws + N_NODES;
    float* dn  = ws + 2 * N_NODES;
    float* P   = ws + 3 * N_NODES;                 // 16*32768 floats = 2 MB
    unsigned short* Bnew = (unsigned short*)(P + NCHUNK * 2 * EDGES);
    unsigned short* Bold = (unsigned short*)(ws + 3 * N_NODES);

    size_t need_new = (3ull * N_NODES + (size_t)NCHUNK * 2 * EDGES) * 4
                      + (size_t)N_NODES * N_NODES * 2;
    size_t need_old = 3ull * N_NODES * 4 + (size_t)N_NODES * N_NODES * 2;

    if (ws_size >= need_new) {
        k_rows_fast<<<N_NODES, 256, 0, stream>>>(A, f0, f1, Bnew, dn);
        k_edges_chunk<<<(2 * EDGES * NCHUNK) / 32, 256, 0, stream>>>(
            Bnew, src0, dst0, src1, dst1, P);
        k_finish<<<(2 * EDGES * 64) / 256, 256, 0, stream>>>(
            P, dn, src0, dst0, src1, dst1,
            p1w1, p1b1, p1w2, p1b2, p2w1, p2b1, p2w2, p2b2, out);
    } else if (ws_size >= need_old) {
        k_prep<<<N_NODES / 256, 256, 0, stream>>>(f0, f1, fm, wsq);
        k_rows_fast<<<N_NODES, 256, 0, stream>>>(A, f0, f1, Bold, dn);
        k_edges_fast<<<(2 * EDGES * 64) / 256, 256, 0, stream>>>(
            Bold, dn, src0, dst0, src1, dst1,
            p1w1, p1b1, p1w2, p1b2, p2w1, p2b1, p2w2, p2b2, out);
    } else {
        k_prep<<<N_NODES / 256, 256, 0, stream>>>(f0, f1, fm, wsq);
        k_rows_slow<<<N_NODES, 256, 0, stream>>>(A, fm, dn);
        k_edges_slow<<<(2 * EDGES * 64) / 256, 256, 0, stream>>>(
            A, wsq, dn, src0, dst0, src1, dst1,
            p1w1, p1b1, p1w2, p1b2, p2w1, p2b1, p2w2, p2b2, out);
    }
}

// Round 7
// 145.733 us; speedup vs baseline: 1.1835x; 1.1835x over previous
//
#include <hip/hip_runtime.h>

#define N_NODES 4096
#define EDGES   16384
#define PHI     64
#define EPS_F   1e-8f
#define BETA_F  0.5f
#define NCHUNK  4
#define WCHUNK  1024   // int8 cols per chunk = 1024 B per row-chunk

#if __has_builtin(__builtin_amdgcn_sdot4)
__device__ __forceinline__ int dot4(int a, int b, int c) {
    return __builtin_amdgcn_sdot4(a, b, c, false);
}
#else
__device__ __forceinline__ int dot4(int a, int b, int c) {
    c += ((a << 24) >> 24) * ((b << 24) >> 24);
    c += ((a << 16) >> 24) * ((b << 16) >> 24);
    c += ((a << 8)  >> 24) * ((b << 8)  >> 24);
    c += (a >> 24) * (b >> 24);
    return c;
}
#endif

__device__ __forceinline__ float wave_sum(float v) {
#pragma unroll
    for (int off = 32; off > 0; off >>= 1) v += __shfl_xor(v, off, 64);
    return v;
}

__device__ __forceinline__ unsigned int pack_bf16(float f) {
    unsigned int u = __float_as_uint(f);
    u += 0x7fffu + ((u >> 16) & 1u);
    return u >> 16;
}

// ---------- int8 fast path ----------

// k0: single block. fm = 0.5*(f0+f1); smax = max|fm|; fmq = fm*127/smax;
// sc[0] = 127/smax, sc[1] = (smax/127)^2.
__global__ void __launch_bounds__(1024) k_prep_q(const float* __restrict__ f0,
                                                 const float* __restrict__ f1,
                                                 float* __restrict__ fm,
                                                 float* __restrict__ fmq,
                                                 float* __restrict__ sc) {
    int t = threadIdx.x;
    float4 a = ((const float4*)f0)[t];
    float4 b = ((const float4*)f1)[t];
    float4 m;
    m.x = 0.5f * (a.x + b.x); m.y = 0.5f * (a.y + b.y);
    m.z = 0.5f * (a.z + b.z); m.w = 0.5f * (a.w + b.w);
    ((float4*)fm)[t] = m;
    float mx = fmaxf(fmaxf(fabsf(m.x), fabsf(m.y)), fmaxf(fabsf(m.z), fabsf(m.w)));
#pragma unroll
    for (int off = 32; off > 0; off >>= 1) mx = fmaxf(mx, __shfl_xor(mx, off, 64));
    __shared__ float red[16];
    __shared__ float s_scale;
    int lane = t & 63, wid = t >> 6;
    if (lane == 0) red[wid] = mx;
    __syncthreads();
    if (t == 0) {
        float s = red[0];
#pragma unroll
        for (int i = 1; i < 16; ++i) s = fmaxf(s, red[i]);
        s = fmaxf(s, 1e-20f);
        s_scale = 127.f / s;
        sc[0] = 127.f / s;
        sc[1] = (s / 127.f) * (s / 127.f);
    }
    __syncthreads();
    float q = s_scale;
    float4 mq;
    mq.x = m.x * q; mq.y = m.y * q; mq.z = m.z * q; mq.w = m.w * q;
    ((float4*)fmq)[t] = mq;
}

// k1: Bq[v,n] = rint(A[v,n]*fmq[n]) packed int8; dnorm[v] = ||A[v,:]*fm + eps||
__global__ void __launch_bounds__(256) k_rows_q(const float* __restrict__ A,
                                                const float* __restrict__ fm,
                                                const float* __restrict__ fmq,
                                                int* __restrict__ Bq,
                                                float* __restrict__ dnorm) {
    int row = blockIdx.x;
    const float4* a4 = (const float4*)(A + (size_t)row * N_NODES);
    const float4* m4 = (const float4*)fm;
    const float4* q4 = (const float4*)fmq;
    int* brow = Bq + (size_t)row * (N_NODES / 4);
    int t = threadIdx.x;
    float acc = 0.f;
#pragma unroll
    for (int i = 0; i < 4; ++i) {
        int idx = i * 256 + t;
        float4 a = a4[idx];
        float4 m = m4[idx];
        float4 mq = q4[idx];
        float b0 = a.x * m.x, b1 = a.y * m.y, b2 = a.z * m.z, b3 = a.w * m.w;
        float e0 = b0 + EPS_F, e1 = b1 + EPS_F, e2 = b2 + EPS_F, e3 = b3 + EPS_F;
        acc += e0 * e0 + e1 * e1 + e2 * e2 + e3 * e3;
        int q0 = __float2int_rn(a.x * mq.x) & 255;
        int q1 = __float2int_rn(a.y * mq.y) & 255;
        int q2 = __float2int_rn(a.z * mq.z) & 255;
        int q3 = __float2int_rn(a.w * mq.w);
        brow[idx] = q0 | (q1 << 8) | (q2 << 16) | (q3 << 24);
    }
    acc = wave_sum(acc);
    __shared__ float red[4];
    if ((t & 63) == 0) red[t >> 6] = acc;
    __syncthreads();
    if (t == 0) dnorm[row] = sqrtf(red[0] + red[1] + red[2] + red[3]);
}

// k2: int8 edge dots. chunk = blk & 3; 8 lanes/edge, 8 edges/wave; per-row
// chunk = 1024 B (8 int4 loads/lane in two passes). Exact int32 accumulate.
__global__ void __launch_bounds__(256, 8) k_edges_i8(
        const char* __restrict__ B,
        const int* __restrict__ src0, const int* __restrict__ dst0,
        const int* __restrict__ src1, const int* __restrict__ dst1,
        int* __restrict__ P) {
    int blk   = blockIdx.x;
    int chunk = blk & (NCHUNK - 1);
    int slot  = blk >> 2;                      // [0, 1024)
    int wave  = threadIdx.x >> 6;
    int lane  = threadIdx.x & 63;
    int g     = lane >> 3;
    int sub   = lane & 7;

    int ge  = slot * 32 + wave * 8 + g;        // [0, 32768)
    int lid = ge >> 14;
    int e   = ge & (EDGES - 1);
    int s = lid ? src1[e] : src0[e];
    int d = lid ? dst1[e] : dst0[e];

    const int4* rs = (const int4*)(B + (size_t)s * N_NODES + chunk * WCHUNK) + sub;
    const int4* rd = (const int4*)(B + (size_t)d * N_NODES + chunk * WCHUNK) + sub;

    int acc = 0;
#pragma unroll
    for (int h = 0; h < 2; ++h) {
        int4 us[4], ud[4];
#pragma unroll
        for (int i = 0; i < 4; ++i) {
            us[i] = rs[(h * 4 + i) * 8];
            ud[i] = rd[(h * 4 + i) * 8];
        }
#pragma unroll
        for (int i = 0; i < 4; ++i) {
            acc = dot4(us[i].x, ud[i].x, acc);
            acc = dot4(us[i].y, ud[i].y, acc);
            acc = dot4(us[i].z, ud[i].z, acc);
            acc = dot4(us[i].w, ud[i].w, acc);
        }
    }
    acc += __shfl_xor(acc, 1, 64);
    acc += __shfl_xor(acc, 2, 64);
    acc += __shfl_xor(acc, 4, 64);
    if (sub == 0) P[(size_t)chunk * (2 * EDGES) + ge] = acc;
}

// Shared epilogue
__device__ __forceinline__ void mlp_epilogue(float x, int lid, int e, int lane,
                                             const float* __restrict__ p1w1, const float* __restrict__ p1b1,
                                             const float* __restrict__ p1w2, const float* __restrict__ p1b2,
                                             const float* __restrict__ p2w1, const float* __restrict__ p2b1,
                                             const float* __restrict__ p2w2, const float* __restrict__ p2b2,
                                             float* __restrict__ out) {
    int wi = lid * PHI + lane;
    float h1 = fmaxf(fmaf(x, p1w1[wi], p1b1[wi]), 0.f);
    float y1 = wave_sum(h1 * p1w2[wi]) + p1b2[lid];
    float sl1 = BETA_F * y1;   // LM = 1.0
    float h2 = fmaxf(fmaf(sl1, p2w1[wi], p2b1[wi]), 0.f);
    float y2 = wave_sum(h2 * p2w2[wi]) + p2b2[lid];
    if (lane == 0) out[lid * EDGES + e] = y2;
}

// k3: sum 4 int partials, dequant, normalize, both MLPs
__global__ void __launch_bounds__(256) k_finish_i8(
        const int* __restrict__ P, const float* __restrict__ dnorm,
        const float* __restrict__ sc,
        const int* __restrict__ src0, const int* __restrict__ dst0,
        const int* __restrict__ src1, const int* __restrict__ dst1,
        const float* __restrict__ p1w1, const float* __restrict__ p1b1,
        const float* __restrict__ p1w2, const float* __restrict__ p1b2,
        const float* __restrict__ p2w1, const float* __restrict__ p2b1,
        const float* __restrict__ p2w2, const float* __restrict__ p2b2,
        float* __restrict__ out) {
    int gw   = (int)((blockIdx.x * blockDim.x + threadIdx.x) >> 6);   // [0, 32768)
    int lane = threadIdx.x & 63;
    int lid  = gw >> 14;
    int e    = gw & (EDGES - 1);
    int s = lid ? src1[e] : src0[e];
    int d = lid ? dst1[e] : dst0[e];
    int acc = 0;
#pragma unroll
    for (int c = 0; c < NCHUNK; ++c) acc += P[(size_t)c * (2 * EDGES) + gw];
    float x = (float)acc * sc[1] / (dnorm[s] * dnorm[d]);
    mlp_epilogue(x, lid, e, lane, p1w1, p1b1, p1w2, p1b2, p2w1, p2b1, p2w2, p2b2, out);
}

// ---------- bf16 fallback path (ws-constrained) ----------

__global__ void k_prep(const float* __restrict__ f0, const float* __restrict__ f1,
                       float* __restrict__ fm, float* __restrict__ wsq) {
    int i = blockIdx.x * blockDim.x + threadIdx.x;
    if (i < N_NODES) {
        float m = 0.5f * (f0[i] + f1[i]);
        fm[i]  = m;
        wsq[i] = m * m;
    }
}

__global__ void __launch_bounds__(256) k_rows_fast(const float* __restrict__ A,
                                                   const float* __restrict__ f0,
                                                   const float* __restrict__ f1,
                                                   unsigned short* __restrict__ B,
                                                   float* __restrict__ dnorm) {
    int row = blockIdx.x;
    const float4* a4  = (const float4*)(A + (size_t)row * N_NODES);
    const float4* f04 = (const float4*)f0;
    const float4* f14 = (const float4*)f1;
    uint2* b2 = (uint2*)(B + (size_t)row * N_NODES);
    int t = threadIdx.x;
    float acc = 0.f;
#pragma unroll
    for (int i = 0; i < 4; ++i) {
        int idx = i * 256 + t;
        float4 a = a4[idx];
        float4 fa = f04[idx];
        float4 fb = f14[idx];
        float fx = 0.5f * (fa.x + fb.x), fy = 0.5f * (fa.y + fb.y);
        float fz = 0.5f * (fa.z + fb.z), fw = 0.5f * (fa.w + fb.w);
        float b0 = a.x * fx, b1 = a.y * fy, b2v = a.z * fz, b3 = a.w * fw;
        float e0 = b0 + EPS_F, e1 = b1 + EPS_F, e2 = b2v + EPS_F, e3 = b3 + EPS_F;
        acc += e0 * e0 + e1 * e1 + e2 * e2 + e3 * e3;
        uint2 p;
        p.x = (pack_bf16(b1) << 16) | pack_bf16(b0);
        p.y = (pack_bf16(b3) << 16) | pack_bf16(b2v);
        b2[idx] = p;
    }
    acc = wave_sum(acc);
    __shared__ float red[4];
    if ((t & 63) == 0) red[t >> 6] = acc;
    __syncthreads();
    if (t == 0) dnorm[row] = sqrtf(red[0] + red[1] + red[2] + red[3]);
}

__global__ void __launch_bounds__(256) k_rows_slow(const float* __restrict__ A,
                                                   const float* __restrict__ fm,
                                                   float* __restrict__ dnorm) {
    int row = blockIdx.x;
    const float4* a4  = (const float4*)(A + (size_t)row * N_NODES);
    const float4* fm4 = (const float4*)fm;
    int t = threadIdx.x;
    float acc = 0.f;
#pragma unroll
    for (int i = 0; i < 4; ++i) {
        int idx = i * 256 + t;
        float4 a = a4[idx];
        float4 f = fm4[idx];
        float e0 = a.x * f.x + EPS_F, e1 = a.y * f.y + EPS_F;
        float e2 = a.z * f.z + EPS_F, e3 = a.w * f.w + EPS_F;
        acc += e0 * e0 + e1 * e1 + e2 * e2 + e3 * e3;
    }
    acc = wave_sum(acc);
    __shared__ float red[4];
    if ((t & 63) == 0) red[t >> 6] = acc;
    __syncthreads();
    if (t == 0) dnorm[row] = sqrtf(red[0] + red[1] + red[2] + red[3]);
}

__global__ void __launch_bounds__(256) k_edges_fast(
        const unsigned short* __restrict__ B, const float* __restrict__ dnorm,
        const int* __restrict__ src0, const int* __restrict__ dst0,
        const int* __restrict__ src1, const int* __restrict__ dst1,
        const float* __restrict__ p1w1, const float* __restrict__ p1b1,
        const float* __restrict__ p1w2, const float* __restrict__ p1b2,
        const float* __restrict__ p2w1, const float* __restrict__ p2b1,
        const float* __restrict__ p2w2, const float* __restrict__ p2b2,
        float* __restrict__ out) {
    int gw   = (int)((blockIdx.x * blockDim.x + threadIdx.x) >> 6);
    int lane = threadIdx.x & 63;
    int lid  = gw >> 14;
    int e    = gw & (EDGES - 1);
    int s = lid ? src1[e] : src0[e];
    int d = lid ? dst1[e] : dst0[e];
    const uint4* rs = (const uint4*)(B + (size_t)s * N_NODES);
    const uint4* rd = (const uint4*)(B + (size_t)d * N_NODES);
    float acc = 0.f;
#pragma unroll
    for (int i = 0; i < 8; ++i) {
        uint4 us = rs[i * 64 + lane];
        uint4 ud = rd[i * 64 + lane];
#define ACC_U(U, V)                                                    \
        {                                                              \
            float sl = __uint_as_float((U) << 16);                     \
            float sh = __uint_as_float((U) & 0xffff0000u);             \
            float dl = __uint_as_float((V) << 16);                     \
            float dh = __uint_as_float((V) & 0xffff0000u);             \
            acc = fmaf(sl, dl, acc);                                   \
            acc = fmaf(sh, dh, acc);                                   \
        }
        ACC_U(us.x, ud.x); ACC_U(us.y, ud.y); ACC_U(us.z, ud.z); ACC_U(us.w, ud.w);
#undef ACC_U
    }
    acc = wave_sum(acc);
    float x = acc / (dnorm[s] * dnorm[d]);
    mlp_epilogue(x, lid, e, lane, p1w1, p1b1, p1w2, p1b2, p2w1, p2b1, p2w2, p2b2, out);
}

__global__ void __launch_bounds__(256) k_edges_slow(
        const float* __restrict__ A, const float* __restrict__ wsq,
        const float* __restrict__ dnorm,
        const int* __restrict__ src0, const int* __restrict__ dst0,
        const int* __restrict__ src1, const int* __restrict__ dst1,
        const float* __restrict__ p1w1, const float* __restrict__ p1b1,
        const float* __restrict__ p1w2, const float* __restrict__ p1b2,
        const float* __restrict__ p2w1, const float* __restrict__ p2b1,
        const float* __restrict__ p2w2, const float* __restrict__ p2b2,
        float* __restrict__ out) {
    __shared__ float wl[N_NODES];
    int t = threadIdx.x;
    const float4* w4 = (const float4*)wsq;
    float4* wl4 = (float4*)wl;
    for (int i = t; i < N_NODES / 4; i += 256) wl4[i] = w4[i];
    __syncthreads();

    int gw   = (int)((blockIdx.x * blockDim.x + t) >> 6);
    int lane = t & 63;
    int lid  = gw >> 14;
    int e    = gw & (EDGES - 1);
    int s = lid ? src1[e] : src0[e];
    int d = lid ? dst1[e] : dst0[e];
    const float4* rs = (const float4*)(A + (size_t)s * N_NODES);
    const float4* rd = (const float4*)(A + (size_t)d * N_NODES);
    float acc = 0.f;
#pragma unroll
    for (int i = 0; i < 16; ++i) {
        int idx = i * 64 + lane;
        float4 a = rs[idx];
        float4 b = rd[idx];
        float4 w = wl4[idx];
        acc = fmaf(a.x * b.x, w.x, acc);
        acc = fmaf(a.y * b.y, w.y, acc);
        acc = fmaf(a.z * b.z, w.z, acc);
        acc = fmaf(a.w * b.w, w.w, acc);
    }
    acc = wave_sum(acc);
    float x = acc / (dnorm[s] * dnorm[d]);
    mlp_epilogue(x, lid, e, lane, p1w1, p1b1, p1w2, p1b2, p2w1, p2b1, p2w2, p2b2, out);
}

extern "C" void kernel_launch(void* const* d_in, const int* in_sizes, int n_in,
                              void* d_out, int out_size, void* d_ws, size_t ws_size,
                              hipStream_t stream) {
    const float* A    = (const float*)d_in[0];
    const int*   src0 = (const int*)d_in[1];
    const int*   dst0 = (const int*)d_in[2];
    const int*   src1 = (const int*)d_in[3];
    const int*   dst1 = (const int*)d_in[4];
    const float* f0   = (const float*)d_in[5];
    const float* f1   = (const float*)d_in[6];
    const float* p1w1 = (const float*)d_in[7];
    const float* p1b1 = (const float*)d_in[8];
    const float* p1w2 = (const float*)d_in[9];
    const float* p1b2 = (const float*)d_in[10];
    const float* p2w1 = (const float*)d_in[11];
    const float* p2b1 = (const float*)d_in[12];
    const float* p2w2 = (const float*)d_in[13];
    const float* p2b2 = (const float*)d_in[14];
    float* out = (float*)d_out;

    float* ws = (float*)d_ws;
    // int8 path layout (float offsets)
    float* fm   = ws;                      // 4096
    float* fmq  = ws + 4096;               // 4096
    float* dn   = ws + 8192;               // 4096
    float* sc   = ws + 12288;              // 2 (+pad to 12352)
    int*   P    = (int*)(ws + 12352);      // 4*32768 = 131072 ints
    int*   Bq   = (int*)(ws + 12352 + NCHUNK * 2 * EDGES);   // 16 MB
    size_t need_i8 = (12352ull + (size_t)NCHUNK * 2 * EDGES) * 4
                     + (size_t)N_NODES * N_NODES;

    // bf16 fallback layout
    float* wsq  = ws + N_NODES;
    unsigned short* Bold = (unsigned short*)(ws + 3 * N_NODES);
    size_t need_old = 3ull * N_NODES * 4 + (size_t)N_NODES * N_NODES * 2;

    if (ws_size >= need_i8) {
        k_prep_q<<<1, 1024, 0, stream>>>(f0, f1, fm, fmq, sc);
        k_rows_q<<<N_NODES, 256, 0, stream>>>(A, fm, fmq, Bq, dn);
        k_edges_i8<<<(2 * EDGES * NCHUNK) / 32, 256, 0, stream>>>(
            (const char*)Bq, src0, dst0, src1, dst1, P);
        k_finish_i8<<<(2 * EDGES * 64) / 256, 256, 0, stream>>>(
            P, dn, sc, src0, dst0, src1, dst1,
            p1w1, p1b1, p1w2, p1b2, p2w1, p2b1, p2w2, p2b2, out);
    } else if (ws_size >= need_old) {
        k_rows_fast<<<N_NODES, 256, 0, stream>>>(A, f0, f1, Bold, dn);
        k_edges_fast<<<(2 * EDGES * 64) / 256, 256, 0, stream>>>(
            Bold, dn, src0, dst0, src1, dst1,
            p1w1, p1b1, p1w2, p1b2, p2w1, p2b1, p2w2, p2b2, out);
    } else {
        k_prep<<<N_NODES / 256, 256, 0, stream>>>(f0, f1, fm, wsq);
        k_rows_slow<<<N_NODES, 256, 0, stream>>>(A, fm, dn);
        k_edges_slow<<<(2 * EDGES * 64) / 256, 256, 0, stream>>>(
            A, wsq, dn, src0, dst0, src1, dst1,
            p1w1, p1b1, p1w2, p1b2, p2w1, p2b1, p2w2, p2b2, out);
    }
}